// Round 1
// baseline (409.815 us; speedup 1.0000x reference)
//
#include <hip/hip_runtime.h>
#include <hip/hip_bf16.h>
#include <cstdint>
#include <cstddef>

typedef __bf16 bf16;
typedef __attribute__((ext_vector_type(8))) __bf16 bf16x8;
typedef __attribute__((ext_vector_type(4))) __bf16 bf16x4;
typedef __attribute__((ext_vector_type(4))) float floatx4;

static constexpr int D    = 1024;
static constexpr int BT   = 32768;   // 8 * 4096 tokens
static constexpr int M4R  = 8192;    // BT/4
static constexpr int M16R = 2048;    // BT/16

// ---- workspace layout (bytes); total ~94.6 MiB ----
static constexpr size_t WS_XB     = 0;                                 // 64 MiB bf16 clipped x
static constexpr size_t WS_M4B    = WS_XB     + (size_t)BT   * D * 2;  // 16 MiB
static constexpr size_t WS_M16B   = WS_M4B    + (size_t)M4R  * D * 2;  // 4 MiB
static constexpr size_t WS_W1B    = WS_M16B   + (size_t)M16R * D * 2;  // 2 MiB
static constexpr size_t WS_W4B    = WS_W1B    + (size_t)D * D * 2;
static constexpr size_t WS_W16B   = WS_W4B    + (size_t)D * D * 2;
static constexpr size_t WS_LOGITS = WS_W16B   + (size_t)D * D * 2;     // 256 KiB fp32
static constexpr size_t WS_WSN    = WS_LOGITS + (size_t)BT * 2 * 4;    // 64 B

__device__ __forceinline__ float clipf(float v, float lo, float hi) {
  return fminf(fmaxf(v, lo), hi);
}

// async global->LDS, 16B per lane; LDS dest = wave-uniform base + lane*16
__device__ __forceinline__ void gload_lds16(const void* g, void* l) {
  __builtin_amdgcn_global_load_lds(
      (__attribute__((address_space(1))) void*)(uintptr_t)g,
      (__attribute__((address_space(3))) void*)l, 16, 0, 0);
}

// ---------------------------------------------------------------------------
// Kernel 1: weights fp32 -> bf16, and zero the logits accumulator
// blocks 0..3071: 3*1M weight elements, 1024 elems/block
// blocks 3072..3135: zero 65536 logit floats
// ---------------------------------------------------------------------------
__global__ __launch_bounds__(256) void prep_weights(
    const float* __restrict__ W1, const float* __restrict__ W4,
    const float* __restrict__ W16, bf16* __restrict__ W1b,
    bf16* __restrict__ W4b, bf16* __restrict__ W16b,
    float* __restrict__ logits) {
  const int bid = blockIdx.x;
  const int tid = threadIdx.x;
  if (bid < 3072) {
    const unsigned e = (unsigned)bid * 1024u + (unsigned)tid * 4u;
    const int m = e >> 20;
    const unsigned off = e & 0xFFFFFu;
    const float* src = (m == 0) ? W1 : (m == 1) ? W4 : W16;
    bf16* dst = (m == 0) ? W1b : (m == 1) ? W4b : W16b;
    const float4 v = *reinterpret_cast<const float4*>(src + off);
    bf16x4 o;
    o[0] = (bf16)v.x; o[1] = (bf16)v.y; o[2] = (bf16)v.z; o[3] = (bf16)v.w;
    *reinterpret_cast<bf16x4*>(dst + off) = o;
  } else {
    const unsigned idx = (unsigned)(bid - 3072) * 1024u + (unsigned)tid * 4u;
    float4 z = {0.f, 0.f, 0.f, 0.f};
    *reinterpret_cast<float4*>(logits + idx) = z;
  }
}

// ---------------------------------------------------------------------------
// Kernel 2: clip x to +/-4 -> bf16 xb; group means m4 (groups of 4 tokens)
// and m16 (groups of 16) -> bf16. One block per 16-token group.
// ---------------------------------------------------------------------------
__global__ __launch_bounds__(256) void prep_x(
    const float* __restrict__ vt, bf16* __restrict__ xb,
    bf16* __restrict__ m4b, bf16* __restrict__ m16b) {
  const int g16 = blockIdx.x;            // 0..2047
  const int d0 = threadIdx.x * 4;        // 4 dims per thread
  const float* src = vt + (size_t)g16 * 16 * D + d0;
  bf16* xdst = xb + (size_t)g16 * 16 * D + d0;
  float sx16 = 0.f, sy16 = 0.f, sz16 = 0.f, sw16 = 0.f;
  for (int sub = 0; sub < 4; ++sub) {
    float sx = 0.f, sy = 0.f, sz = 0.f, sw = 0.f;
    for (int t = 0; t < 4; ++t) {
      const int tt = sub * 4 + t;
      float4 v = *reinterpret_cast<const float4*>(src + (size_t)tt * D);
      v.x = clipf(v.x, -4.f, 4.f); v.y = clipf(v.y, -4.f, 4.f);
      v.z = clipf(v.z, -4.f, 4.f); v.w = clipf(v.w, -4.f, 4.f);
      sx += v.x; sy += v.y; sz += v.z; sw += v.w;
      bf16x4 o;
      o[0] = (bf16)v.x; o[1] = (bf16)v.y; o[2] = (bf16)v.z; o[3] = (bf16)v.w;
      *reinterpret_cast<bf16x4*>(xdst + (size_t)tt * D) = o;
    }
    bf16x4 o4;
    o4[0] = (bf16)(sx * 0.25f); o4[1] = (bf16)(sy * 0.25f);
    o4[2] = (bf16)(sz * 0.25f); o4[3] = (bf16)(sw * 0.25f);
    *reinterpret_cast<bf16x4*>(m4b + ((size_t)g16 * 4 + sub) * D + d0) = o4;
    sx16 += sx; sy16 += sy; sz16 += sz; sw16 += sw;
  }
  bf16x4 o16;
  const float r = 1.0f / 16.0f;
  o16[0] = (bf16)(sx16 * r); o16[1] = (bf16)(sy16 * r);
  o16[2] = (bf16)(sz16 * r); o16[3] = (bf16)(sw16 * r);
  *reinterpret_cast<bf16x4*>(m16b + (size_t)g16 * D + d0) = o16;
}

// ---------------------------------------------------------------------------
// m97-structure GEMM: C = X[M x 1024] * W[1024 x 1024]^T (W row-major [N][K]).
// 128x128 tile, BK=32, 4 waves (2x2), each wave 4x4 grid of 16x16x32 MFMAs.
// MODE 0: relu(+b1) then fused W2 contraction -> atomicAdd partial logits
// MODE 1: out = clip(clip(acc+b4)*a4)           (writes all rows)
// MODE 2: out = clip(out + clip(acc+b16)*a16)   (RMW, first 256 groups/sample)
// ---------------------------------------------------------------------------
template <int MODE>
__global__ __launch_bounds__(256) void gemm_bt(
    const bf16* __restrict__ X, const bf16* __restrict__ W,
    const float* __restrict__ bias, const float* __restrict__ W2,
    float* __restrict__ logits, const float* __restrict__ wsn,
    float* __restrict__ out) {
  __shared__ __align__(16) bf16 As[128 * 32];
  __shared__ __align__(16) bf16 Bs[128 * 32];
  const int tid = threadIdx.x;
  const int lane = tid & 63;
  const int wave = tid >> 6;
  const int wm = wave & 1;
  const int wn = wave >> 1;
  const int bn = blockIdx.x;   // N tile (8)
  const int bm = blockIdx.y;   // M tile

  // staging: lane l loads 16B = row (l>>2), cols (l&3)*8..+7 of a 16-row chunk
  const int lrow = lane >> 2;
  const int lcol = (lane & 3) * 8;
  const bf16* Ab = X + ((size_t)bm * 128 + lrow) * D + lcol;
  const bf16* Bb = W + ((size_t)bn * 128 + lrow) * D + lcol;

  floatx4 acc[4][4] = {};

  const int fr = lane & 15;
  const int ko = (lane >> 4) * 8;   // 8 consecutive k per lane (A/B operand layout)

  for (int k0 = 0; k0 < D; k0 += 32) {
    __syncthreads();   // prior compute done before overwriting LDS
    for (int c = wave; c < 8; c += 4) {
      gload_lds16(Ab + (size_t)c * 16 * D + k0, &As[c * 16 * 32]);
      gload_lds16(Bb + (size_t)c * 16 * D + k0, &Bs[c * 16 * 32]);
    }
    __syncthreads();   // compiler drains vmcnt(0) before s_barrier
    bf16x8 af[4], bf[4];
    for (int mt = 0; mt < 4; ++mt)
      af[mt] = *reinterpret_cast<const bf16x8*>(&As[(wm * 64 + mt * 16 + fr) * 32 + ko]);
    for (int nt = 0; nt < 4; ++nt)
      bf[nt] = *reinterpret_cast<const bf16x8*>(&Bs[(wn * 64 + nt * 16 + fr) * 32 + ko]);
    for (int mt = 0; mt < 4; ++mt)
      for (int nt = 0; nt < 4; ++nt)
        acc[mt][nt] = __builtin_amdgcn_mfma_f32_16x16x32_bf16(af[mt], bf[nt], acc[mt][nt], 0, 0, 0);
  }

  // C/D layout: col = lane&15 (=fr), row = (lane>>4)*4 + reg
  const int q4 = (lane >> 4) * 4;
  if (MODE == 0) {
    for (int mt = 0; mt < 4; ++mt) {
      for (int r = 0; r < 4; ++r) {
        const int row = bm * 128 + wm * 64 + mt * 16 + q4 + r;   // token id
        float v0 = 0.f, v1 = 0.f;
        for (int nt = 0; nt < 4; ++nt) {
          const int col = bn * 128 + wn * 64 + nt * 16 + fr;
          float h = acc[mt][nt][r] + bias[col];
          h = h > 0.f ? h : 0.f;
          v0 += h * W2[col];
          v1 += h * W2[D + col];
        }
        // reduce across the 16 lanes sharing this row (xor bits 0..3)
        for (int mask = 1; mask < 16; mask <<= 1) {
          v0 += __shfl_xor(v0, mask, 64);
          v1 += __shfl_xor(v1, mask, 64);
        }
        if (fr == 0) {
          unsafeAtomicAdd(&logits[row * 2 + 0], v0);
          unsafeAtomicAdd(&logits[row * 2 + 1], v1);
        }
      }
    }
  } else if (MODE == 1) {
    for (int mt = 0; mt < 4; ++mt) {
      for (int r = 0; r < 4; ++r) {
        const int row = bm * 128 + wm * 64 + mt * 16 + q4 + r;   // 0..8191
        const float a4 = wsn[(row >> 10) * 2 + 0];
        float* orow = out + (size_t)row * D;
        for (int nt = 0; nt < 4; ++nt) {
          const int col = bn * 128 + wn * 64 + nt * 16 + fr;
          const float v = clipf(acc[mt][nt][r] + bias[col], -6.f, 6.f) * a4;
          orow[col] = clipf(v, -6.f, 6.f);
        }
      }
    }
  } else {
    for (int mt = 0; mt < 4; ++mt) {
      for (int r = 0; r < 4; ++r) {
        const int row = bm * 128 + wm * 64 + mt * 16 + q4 + r;   // 0..2047
        const int b = row >> 8;
        const int g = row & 255;
        const float a16 = wsn[b * 2 + 1];
        float* orow = out + ((size_t)b * 1024 + g) * D;
        for (int nt = 0; nt < 4; ++nt) {
          const int col = bn * 128 + wn * 64 + nt * 16 + fr;
          const float v = clipf(acc[mt][nt][r] + bias[col], -6.f, 6.f) * a16;
          orow[col] = clipf(orow[col] + v, -6.f, 6.f);
        }
      }
    }
  }
}

// ---------------------------------------------------------------------------
// Kernel 4: gumbel-softmax per token, mean per sample, normalized mix weights
// ---------------------------------------------------------------------------
__global__ __launch_bounds__(256) void reduce_probs(
    const float* __restrict__ logits, const float* __restrict__ gumbel,
    const float* __restrict__ b2, float* __restrict__ wsn) {
  const int b = blockIdx.x;
  const int tid = threadIdx.x;
  float s0 = 0.f, s1 = 0.f;
  for (int i = tid; i < 4096; i += 256) {
    const int t = b * 4096 + i;
    const float l0 = clipf(logits[t * 2 + 0] + b2[0], -15.f, 15.f);
    const float l1 = clipf(logits[t * 2 + 1] + b2[1], -15.f, 15.f);
    // softmax over 2 at temp 0.5 == sigmoid of 2*(z0-z1)
    const float d = ((l0 + gumbel[t * 2 + 0]) - (l1 + gumbel[t * 2 + 1])) * 2.0f;
    float p0 = 1.0f / (1.0f + expf(-d));
    float p1 = 1.0f / (1.0f + expf(d));
    p0 = clipf(p0, 1e-7f, 1.0f - 1e-7f);
    p1 = clipf(p1, 1e-7f, 1.0f - 1e-7f);
    s0 += p0; s1 += p1;
  }
  for (int mask = 1; mask < 64; mask <<= 1) {
    s0 += __shfl_xor(s0, mask, 64);
    s1 += __shfl_xor(s1, mask, 64);
  }
  __shared__ float r0[4], r1[4];
  const int wave = tid >> 6;
  const int lane = tid & 63;
  if (lane == 0) { r0[wave] = s0; r1[wave] = s1; }
  __syncthreads();
  if (tid == 0) {
    const float w4  = (r0[0] + r0[1] + r0[2] + r0[3]) * (1.0f / 4096.0f);
    const float w16 = (r1[0] + r1[1] + r1[2] + r1[3]) * (1.0f / 4096.0f);
    const float ws = w4 + w16 + 1e-7f;
    wsn[b * 2 + 0] = w4 / ws;
    wsn[b * 2 + 1] = w16 / ws;
  }
}

extern "C" void kernel_launch(void* const* d_in, const int* in_sizes, int n_in,
                              void* d_out, int out_size, void* d_ws, size_t ws_size,
                              hipStream_t stream) {
  (void)in_sizes; (void)n_in; (void)out_size; (void)ws_size;
  const float* vt  = (const float*)d_in[0];
  const float* gum = (const float*)d_in[1];
  const float* W1  = (const float*)d_in[2];
  const float* b1  = (const float*)d_in[3];
  const float* W2  = (const float*)d_in[4];
  const float* b2  = (const float*)d_in[5];
  const float* W4  = (const float*)d_in[6];
  const float* b4  = (const float*)d_in[7];
  const float* W16 = (const float*)d_in[8];
  const float* b16 = (const float*)d_in[9];
  float* out = (float*)d_out;
  char* ws = (char*)d_ws;

  bf16* xb     = (bf16*)(ws + WS_XB);
  bf16* m4b    = (bf16*)(ws + WS_M4B);
  bf16* m16b   = (bf16*)(ws + WS_M16B);
  bf16* W1b    = (bf16*)(ws + WS_W1B);
  bf16* W4b    = (bf16*)(ws + WS_W4B);
  bf16* W16b   = (bf16*)(ws + WS_W16B);
  float* logits = (float*)(ws + WS_LOGITS);
  float* wsn   = (float*)(ws + WS_WSN);

  hipLaunchKernelGGL(prep_weights, dim3(3136), dim3(256), 0, stream,
                     W1, W4, W16, W1b, W4b, W16b, logits);
  hipLaunchKernelGGL(prep_x, dim3(2048), dim3(256), 0, stream, vt, xb, m4b, m16b);
  hipLaunchKernelGGL((gemm_bt<0>), dim3(8, 256), dim3(256), 0, stream,
                     xb, W1b, b1, W2, logits, nullptr, nullptr);
  hipLaunchKernelGGL(reduce_probs, dim3(8), dim3(256), 0, stream, logits, gum, b2, wsn);
  hipLaunchKernelGGL((gemm_bt<1>), dim3(8, 64), dim3(256), 0, stream,
                     m4b, W4b, b4, nullptr, nullptr, wsn, out);
  hipLaunchKernelGGL((gemm_bt<2>), dim3(8, 16), dim3(256), 0, stream,
                     m16b, W16b, b16, nullptr, nullptr, wsn, out);
}

// Round 2
// 390.590 us; speedup vs baseline: 1.0492x; 1.0492x over previous
//
#include <hip/hip_runtime.h>
#include <hip/hip_bf16.h>
#include <cstdint>
#include <cstddef>

typedef __bf16 bf16;
typedef __attribute__((ext_vector_type(8))) __bf16 bf16x8;
typedef __attribute__((ext_vector_type(4))) __bf16 bf16x4;
typedef __attribute__((ext_vector_type(4))) float floatx4;

static constexpr int D    = 1024;
static constexpr int BT   = 32768;   // 8 * 4096 tokens
static constexpr int M4R  = 8192;    // BT/4
static constexpr int M16R = 2048;    // BT/16

// ---- workspace layout (bytes); total ~102.6 MiB ----
static constexpr size_t WS_XB     = 0;                                 // 64 MiB bf16 clipped x
static constexpr size_t WS_M4B    = WS_XB     + (size_t)BT   * D * 2;  // 16 MiB
static constexpr size_t WS_M16B   = WS_M4B    + (size_t)M4R  * D * 2;  // 4 MiB
static constexpr size_t WS_W1B    = WS_M16B   + (size_t)M16R * D * 2;  // 2 MiB
static constexpr size_t WS_W4B    = WS_W1B    + (size_t)D * D * 2;
static constexpr size_t WS_W16B   = WS_W4B    + (size_t)D * D * 2;
static constexpr size_t WS_LOGITS = WS_W16B   + (size_t)D * D * 2;     // 256 KiB fp32
static constexpr size_t WS_WSN    = WS_LOGITS + (size_t)BT * 2 * 4;    // 64 B
static constexpr size_t WS_C16C   = WS_WSN    + 64;                    // 8 MiB fp32

__device__ __forceinline__ float clipf(float v, float lo, float hi) {
  return fminf(fmaxf(v, lo), hi);
}

// async global->LDS, 16B per lane; LDS dest = wave-uniform base + lane*16,
// but the GLOBAL address is per-lane -> we can permute lanes to swizzle LDS.
__device__ __forceinline__ void gload_lds16(const void* g, void* l) {
  __builtin_amdgcn_global_load_lds(
      (__attribute__((address_space(1))) void*)(uintptr_t)g,
      (__attribute__((address_space(3))) void*)l, 16, 0, 0);
}

// ---------------------------------------------------------------------------
// Kernel 1 (fused prep): weight fp32->bf16 casts, zero logits, clip x + group
// means. blocks 0..3071 weights; 3072..3135 zero logits; 3136..5183 prep_x.
// ---------------------------------------------------------------------------
__global__ __launch_bounds__(256) void prep_all(
    const float* __restrict__ vt, const float* __restrict__ W1,
    const float* __restrict__ W4, const float* __restrict__ W16,
    bf16* __restrict__ xb, bf16* __restrict__ m4b, bf16* __restrict__ m16b,
    bf16* __restrict__ W1b, bf16* __restrict__ W4b, bf16* __restrict__ W16b,
    float* __restrict__ logits) {
  const int bid = blockIdx.x;
  const int tid = threadIdx.x;
  if (bid < 3072) {
    const unsigned e = (unsigned)bid * 1024u + (unsigned)tid * 4u;
    const int m = e >> 20;
    const unsigned off = e & 0xFFFFFu;
    const float* src = (m == 0) ? W1 : (m == 1) ? W4 : W16;
    bf16* dst = (m == 0) ? W1b : (m == 1) ? W4b : W16b;
    const float4 v = *reinterpret_cast<const float4*>(src + off);
    bf16x4 o;
    o[0] = (bf16)v.x; o[1] = (bf16)v.y; o[2] = (bf16)v.z; o[3] = (bf16)v.w;
    *reinterpret_cast<bf16x4*>(dst + off) = o;
  } else if (bid < 3136) {
    const unsigned idx = (unsigned)(bid - 3072) * 1024u + (unsigned)tid * 4u;
    float4 z = {0.f, 0.f, 0.f, 0.f};
    *reinterpret_cast<float4*>(logits + idx) = z;
  } else {
    const int g16 = bid - 3136;          // 0..2047
    const int d0 = tid * 4;
    const float* src = vt + (size_t)g16 * 16 * D + d0;
    bf16* xdst = xb + (size_t)g16 * 16 * D + d0;
    float sx16 = 0.f, sy16 = 0.f, sz16 = 0.f, sw16 = 0.f;
    for (int sub = 0; sub < 4; ++sub) {
      float sx = 0.f, sy = 0.f, sz = 0.f, sw = 0.f;
      for (int t = 0; t < 4; ++t) {
        const int tt = sub * 4 + t;
        float4 v = *reinterpret_cast<const float4*>(src + (size_t)tt * D);
        v.x = clipf(v.x, -4.f, 4.f); v.y = clipf(v.y, -4.f, 4.f);
        v.z = clipf(v.z, -4.f, 4.f); v.w = clipf(v.w, -4.f, 4.f);
        sx += v.x; sy += v.y; sz += v.z; sw += v.w;
        bf16x4 o;
        o[0] = (bf16)v.x; o[1] = (bf16)v.y; o[2] = (bf16)v.z; o[3] = (bf16)v.w;
        *reinterpret_cast<bf16x4*>(xdst + (size_t)tt * D) = o;
      }
      bf16x4 o4;
      o4[0] = (bf16)(sx * 0.25f); o4[1] = (bf16)(sy * 0.25f);
      o4[2] = (bf16)(sz * 0.25f); o4[3] = (bf16)(sw * 0.25f);
      *reinterpret_cast<bf16x4*>(m4b + ((size_t)g16 * 4 + sub) * D + d0) = o4;
      sx16 += sx; sy16 += sy; sz16 += sz; sw16 += sw;
    }
    bf16x4 o16;
    const float r = 1.0f / 16.0f;
    o16[0] = (bf16)(sx16 * r); o16[1] = (bf16)(sy16 * r);
    o16[2] = (bf16)(sz16 * r); o16[3] = (bf16)(sw16 * r);
    *reinterpret_cast<bf16x4*>(m16b + (size_t)g16 * D + d0) = o16;
  }
}

// ---------------------------------------------------------------------------
// Kernel 2 (fused GEMM): all three GEMMs in one grid (8, 336).
// bm<256: h = relu(xb.W1^T + b1) -> fused W2 contraction -> atomic logits
// 256<=bm<320: out(rows)  = clip(m4b.W4^T  + b4, +-6)    (unscaled fp32)
// bm>=320:     c16c(rows) = clip(m16b.W16^T + b16, +-6)  (unscaled fp32)
// 128x128 tile, BK=64 (16 barrier pairs), 16x16x32 MFMA, swizzled LDS.
// ---------------------------------------------------------------------------
__global__ __launch_bounds__(256) void gemm_fused(
    const bf16* __restrict__ xb, const bf16* __restrict__ m4b,
    const bf16* __restrict__ m16b, const bf16* __restrict__ W1b,
    const bf16* __restrict__ W4b, const bf16* __restrict__ W16b,
    const float* __restrict__ b1, const float* __restrict__ b4,
    const float* __restrict__ b16, const float* __restrict__ W2,
    float* __restrict__ logits, float* __restrict__ out,
    float* __restrict__ c16c) {
  __shared__ __align__(16) bf16 As[128 * 64];
  __shared__ __align__(16) bf16 Bs[128 * 64];
  const int tid = threadIdx.x;
  const int lane = tid & 63;
  const int wave = tid >> 6;
  const int wm = wave & 1;
  const int wn = wave >> 1;
  const int bn = blockIdx.x;
  int bm = blockIdx.y;
  int mode;
  const bf16 *X, *W;
  const float* bias;
  if (bm < 256)      { mode = 0; X = xb;   W = W1b;  bias = b1;  }
  else if (bm < 320) { mode = 1; X = m4b;  W = W4b;  bias = b4;  bm -= 256; }
  else               { mode = 2; X = m16b; W = W16b; bias = b16; bm -= 320; }

  // staging (swizzled): lane -> local row lr = lane>>3 of an 8-row chunk,
  // fetches global 16B colblock jb so it lands at LDS slot (lane&7).
  // LDS image: elem addr = chunk*512 + r*64 + ((j + r)&7)*8   (r local row)
  const int lr = lane >> 3;
  const int jb = ((lane & 7) - lr) & 7;
  const bf16* Ab = X + ((size_t)bm * 128 + lr) * D + jb * 8;
  const bf16* Bb = W + ((size_t)bn * 128 + lr) * D + jb * 8;

  floatx4 acc[4][4] = {};

  const int fr = lane & 15;     // MFMA fragment row
  const int q  = lane >> 4;     // quad id: k-offset = q*8 (+ kk*32)
  const int r7 = fr & 7;
  const int rbase_m = (wm * 8 + (fr >> 3)) * 512 + r7 * 64;
  const int rbase_n = (wn * 8 + (fr >> 3)) * 512 + r7 * 64;

  for (int k0 = 0; k0 < D; k0 += 64) {
    __syncthreads();   // prior compute done before overwriting LDS
    for (int c = wave; c < 16; c += 4) {
      gload_lds16(Ab + (size_t)c * 8 * D + k0, &As[c * 512]);
      gload_lds16(Bb + (size_t)c * 8 * D + k0, &Bs[c * 512]);
    }
    __syncthreads();   // drains vmcnt(0) before s_barrier
#pragma unroll
    for (int kk = 0; kk < 2; ++kk) {
      const int sw = ((kk * 4 + q + r7) & 7) * 8;   // swizzled colblock
      bf16x8 af[4], bfr[4];
#pragma unroll
      for (int t = 0; t < 4; ++t)
        af[t] = *reinterpret_cast<const bf16x8*>(&As[rbase_m + t * 1024 + sw]);
#pragma unroll
      for (int t = 0; t < 4; ++t)
        bfr[t] = *reinterpret_cast<const bf16x8*>(&Bs[rbase_n + t * 1024 + sw]);
#pragma unroll
      for (int mt = 0; mt < 4; ++mt)
#pragma unroll
        for (int nt = 0; nt < 4; ++nt)
          acc[mt][nt] = __builtin_amdgcn_mfma_f32_16x16x32_bf16(af[mt], bfr[nt], acc[mt][nt], 0, 0, 0);
    }
  }

  // C/D layout: col = lane&15 (=fr), row = q*4 + reg
  const int q4 = q * 4;
  if (mode == 0) {
    float bv[4], w2a[4], w2b[4];
#pragma unroll
    for (int nt = 0; nt < 4; ++nt) {
      const int col = bn * 128 + wn * 64 + nt * 16 + fr;
      bv[nt] = bias[col]; w2a[nt] = W2[col]; w2b[nt] = W2[D + col];
    }
    for (int mt = 0; mt < 4; ++mt) {
      for (int r = 0; r < 4; ++r) {
        const int row = bm * 128 + wm * 64 + mt * 16 + q4 + r;   // token id
        float v0 = 0.f, v1 = 0.f;
#pragma unroll
        for (int nt = 0; nt < 4; ++nt) {
          float h = acc[mt][nt][r] + bv[nt];
          h = fmaxf(h, 0.f);
          v0 += h * w2a[nt];
          v1 += h * w2b[nt];
        }
        for (int m = 1; m < 16; m <<= 1) {
          v0 += __shfl_xor(v0, m, 64);
          v1 += __shfl_xor(v1, m, 64);
        }
        if (fr == 0) {
          unsafeAtomicAdd(&logits[row * 2 + 0], v0);
          unsafeAtomicAdd(&logits[row * 2 + 1], v1);
        }
      }
    }
  } else if (mode == 1) {
    float bv[4];
#pragma unroll
    for (int nt = 0; nt < 4; ++nt)
      bv[nt] = bias[bn * 128 + wn * 64 + nt * 16 + fr];
    for (int mt = 0; mt < 4; ++mt) {
      for (int r = 0; r < 4; ++r) {
        const int row = bm * 128 + wm * 64 + mt * 16 + q4 + r;   // 0..8191
        float* orow = out + (size_t)row * D;
#pragma unroll
        for (int nt = 0; nt < 4; ++nt) {
          const int col = bn * 128 + wn * 64 + nt * 16 + fr;
          orow[col] = clipf(acc[mt][nt][r] + bv[nt], -6.f, 6.f);
        }
      }
    }
  } else {
    float bv[4];
#pragma unroll
    for (int nt = 0; nt < 4; ++nt)
      bv[nt] = bias[bn * 128 + wn * 64 + nt * 16 + fr];
    for (int mt = 0; mt < 4; ++mt) {
      for (int r = 0; r < 4; ++r) {
        const int row = bm * 128 + wm * 64 + mt * 16 + q4 + r;   // 0..2047
        float* orow = c16c + (size_t)row * D;
#pragma unroll
        for (int nt = 0; nt < 4; ++nt) {
          const int col = bn * 128 + wn * 64 + nt * 16 + fr;
          orow[col] = clipf(acc[mt][nt][r] + bv[nt], -6.f, 6.f);
        }
      }
    }
  }
}

// ---------------------------------------------------------------------------
// Kernel 3: gumbel-softmax per token, mean per sample, normalized mix weights
// ---------------------------------------------------------------------------
__global__ __launch_bounds__(256) void reduce_probs(
    const float* __restrict__ logits, const float* __restrict__ gumbel,
    const float* __restrict__ b2, float* __restrict__ wsn) {
  const int b = blockIdx.x;
  const int tid = threadIdx.x;
  float s0 = 0.f, s1 = 0.f;
  for (int i = tid; i < 4096; i += 256) {
    const int t = b * 4096 + i;
    const float l0 = clipf(logits[t * 2 + 0] + b2[0], -15.f, 15.f);
    const float l1 = clipf(logits[t * 2 + 1] + b2[1], -15.f, 15.f);
    const float d = ((l0 + gumbel[t * 2 + 0]) - (l1 + gumbel[t * 2 + 1])) * 2.0f;
    float p0 = 1.0f / (1.0f + expf(-d));
    float p1 = 1.0f / (1.0f + expf(d));
    p0 = clipf(p0, 1e-7f, 1.0f - 1e-7f);
    p1 = clipf(p1, 1e-7f, 1.0f - 1e-7f);
    s0 += p0; s1 += p1;
  }
  for (int mask = 1; mask < 64; mask <<= 1) {
    s0 += __shfl_xor(s0, mask, 64);
    s1 += __shfl_xor(s1, mask, 64);
  }
  __shared__ float r0[4], r1[4];
  const int wv = tid >> 6;
  const int lane = tid & 63;
  if (lane == 0) { r0[wv] = s0; r1[wv] = s1; }
  __syncthreads();
  if (tid == 0) {
    const float w4  = (r0[0] + r0[1] + r0[2] + r0[3]) * (1.0f / 4096.0f);
    const float w16 = (r1[0] + r1[1] + r1[2] + r1[3]) * (1.0f / 4096.0f);
    const float ws = w4 + w16 + 1e-7f;
    wsn[b * 2 + 0] = w4 / ws;
    wsn[b * 2 + 1] = w16 / ws;
  }
}

// ---------------------------------------------------------------------------
// Kernel 4: out = clip(a4*c4c + a16*c16c_padded, +-6). One block per row.
// ---------------------------------------------------------------------------
__global__ __launch_bounds__(256) void mix_out(
    const float* __restrict__ wsn, const float* __restrict__ c16c,
    float* __restrict__ out) {
  const unsigned i4 = blockIdx.x * 256u + threadIdx.x;  // float4 index
  const int b = i4 >> 18;                               // 262144 float4 / sample
  const unsigned f = i4 & 262143u;
  const int l = f >> 8;                                 // row in sample, 0..1023
  const float a4 = wsn[b * 2 + 0];
  const float a16 = wsn[b * 2 + 1];
  float4 v = *reinterpret_cast<const float4*>(out + (size_t)i4 * 4);
  float4 o;
  if (l < 256) {
    const float4 c = *reinterpret_cast<const float4*>(
        c16c + ((size_t)(b * 256 + l) * 1024) + (f & 255u) * 4);
    o.x = clipf(a4 * v.x + a16 * c.x, -6.f, 6.f);
    o.y = clipf(a4 * v.y + a16 * c.y, -6.f, 6.f);
    o.z = clipf(a4 * v.z + a16 * c.z, -6.f, 6.f);
    o.w = clipf(a4 * v.w + a16 * c.w, -6.f, 6.f);
  } else {
    o.x = clipf(a4 * v.x, -6.f, 6.f);
    o.y = clipf(a4 * v.y, -6.f, 6.f);
    o.z = clipf(a4 * v.z, -6.f, 6.f);
    o.w = clipf(a4 * v.w, -6.f, 6.f);
  }
  *reinterpret_cast<float4*>(out + (size_t)i4 * 4) = o;
}

extern "C" void kernel_launch(void* const* d_in, const int* in_sizes, int n_in,
                              void* d_out, int out_size, void* d_ws, size_t ws_size,
                              hipStream_t stream) {
  (void)in_sizes; (void)n_in; (void)out_size; (void)ws_size;
  const float* vt  = (const float*)d_in[0];
  const float* gum = (const float*)d_in[1];
  const float* W1  = (const float*)d_in[2];
  const float* b1  = (const float*)d_in[3];
  const float* W2  = (const float*)d_in[4];
  const float* b2  = (const float*)d_in[5];
  const float* W4  = (const float*)d_in[6];
  const float* b4  = (const float*)d_in[7];
  const float* W16 = (const float*)d_in[8];
  const float* b16 = (const float*)d_in[9];
  float* out = (float*)d_out;
  char* ws = (char*)d_ws;

  bf16* xb      = (bf16*)(ws + WS_XB);
  bf16* m4b     = (bf16*)(ws + WS_M4B);
  bf16* m16b    = (bf16*)(ws + WS_M16B);
  bf16* W1b     = (bf16*)(ws + WS_W1B);
  bf16* W4b     = (bf16*)(ws + WS_W4B);
  bf16* W16b    = (bf16*)(ws + WS_W16B);
  float* logits = (float*)(ws + WS_LOGITS);
  float* wsn    = (float*)(ws + WS_WSN);
  float* c16c   = (float*)(ws + WS_C16C);

  hipLaunchKernelGGL(prep_all, dim3(5184), dim3(256), 0, stream,
                     vt, W1, W4, W16, xb, m4b, m16b, W1b, W4b, W16b, logits);
  hipLaunchKernelGGL(gemm_fused, dim3(8, 336), dim3(256), 0, stream,
                     xb, m4b, m16b, W1b, W4b, W16b, b1, b4, b16, W2,
                     logits, out, c16c);
  hipLaunchKernelGGL(reduce_probs, dim3(8), dim3(256), 0, stream,
                     logits, gum, b2, wsn);
  hipLaunchKernelGGL(mix_out, dim3(8192), dim3(256), 0, stream,
                     wsn, c16c, out);
}